// Round 5
// baseline (509.849 us; speedup 1.0000x reference)
//
#include <hip/hip_runtime.h>
#include <stdint.h>

typedef __bf16 bf16;
typedef __bf16 bf16x8 __attribute__((ext_vector_type(8)));
typedef float  f32x4  __attribute__((ext_vector_type(4)));

#define NVALID 2080            // D*(D+1)/2 valid (h<=w) pixels
#define NCOLS  16640           // B*NVALID  (bm rows, n-dim)
#define KDIM   4096            // C2D*NS    (bm cols, k-dim)

// ws layout (bytes)
#define OFF_XB    0u           // bf16 [1024][256]
#define OFF_W3B   524288u      // bf16 [512][4096]
#define OFF_W2B   4718592u     // bf16 [128][512]
#define OFF_CVEC  4849664u     // f32  [128]
#define OFF_PIX   4850176u     // int  [2080]
#define OFF_MASKT 8388608u     // bf16 [2080][32][256] = 34,078,720 B
                               // (after gemm2: reused as fp32 partial [16640][512] — same size)
#define OFF_BM    42991616u    // bf16 [16640][4096] = 136,314,880 B; ends 179,306,496
#define OFF_X3T   179306496u   // bf16 [16640][512] = 17,039,360 B (split mode; tail)
#define WS_SPLIT  196345856u   // required ws for split-K mode

__device__ __forceinline__ void gload_lds16(const void* g, void* l) {
    __builtin_amdgcn_global_load_lds(
        (const __attribute__((address_space(1))) void*)g,
        (__attribute__((address_space(3))) void*)l, 16, 0, 0);
}

// Stage 16 rows x 32 k (bf16) into LDS with XOR swizzle: LDS slot (row, c)
// holds global chunk c ^ ((row>>1)&3). ldsbase+rbase*32 is wave-uniform.
__device__ __forceinline__ void stage16(const bf16* gbase, int stride, int rbase,
                                        int k0, bf16* ldsbase, int lane) {
    int row = rbase + (lane >> 2);
    int cg  = (lane & 3) ^ ((row >> 1) & 3);
    gload_lds16(gbase + (size_t)row * stride + k0 + cg * 8, ldsbase + rbase * 32);
}

// Read one MFMA A/B fragment (8 k-contig bf16) from a swizzled [rows][32] tile.
__device__ __forceinline__ bf16x8 fragld(const bf16* lds, int row, int q) {
    int c = q ^ ((row >> 1) & 3);
    return *(const bf16x8*)(lds + row * 32 + c * 8);
}

// ---------------- conv1d(k=3,pad=1) + relu + cast -> xb[b*128+co][t] ---------
__global__ __launch_bounds__(256) void k_conv(const float* __restrict__ base,
                                              const float* __restrict__ w1,
                                              const float* __restrict__ b1,
                                              bf16* __restrict__ xb) {
    __shared__ float sb[256][10];
    int ttile = blockIdx.x, b = blockIdx.y;
    int t0 = ttile * 8, tid = threadIdx.x;
    for (int ci = tid; ci < 256; ci += 256) {
        const float* src = base + (size_t)(b * 256 + ci) * 256;
        #pragma unroll
        for (int j = 0; j < 10; j++) {
            int t = t0 - 1 + j;
            sb[ci][j] = (t >= 0 && t < 256) ? src[t] : 0.f;
        }
    }
    __syncthreads();
    int co = tid & 127, th = tid >> 7;
    float bias = b1[co];
    float acc[4] = {bias, bias, bias, bias};
    const float* wp = w1 + (size_t)co * 768;
    int tl = th * 4;
    for (int ci = 0; ci < 256; ci++) {
        float wa = wp[ci*3+0], wb = wp[ci*3+1], wc = wp[ci*3+2];
        #pragma unroll
        for (int j = 0; j < 4; j++)
            acc[j] += sb[ci][tl+j]*wa + sb[ci][tl+j+1]*wb + sb[ci][tl+j+2]*wc;
    }
    bf16* dst = xb + (size_t)(b * 128 + co) * 256 + t0 + tl;
    #pragma unroll
    for (int j = 0; j < 4; j++) {
        float v = acc[j] > 0.f ? acc[j] : 0.f;
        dst[j] = (bf16)v;
    }
}

// ---------------- misc: cvec, pix2hw, w2 cast, w3 cast (merged) --------------
__global__ __launch_bounds__(256) void k_misc(const float* __restrict__ w2,
                                              const float* __restrict__ b2,
                                              const float* __restrict__ b3,
                                              const float* __restrict__ w3,
                                              bf16* __restrict__ w2b,
                                              bf16* __restrict__ w3b,
                                              float* __restrict__ cvec,
                                              int* __restrict__ pix2hw) {
    int tid = threadIdx.x;
    if (blockIdx.x == 0) {
        if (tid < 128) {
            float s = b2[tid];
            for (int o = 0; o < 512; o++) {
                float r = b3[o]; r = r > 0.f ? r : 0.f;
                s += w2[(size_t)tid * 512 + o] * r;
            }
            cvec[tid] = s > 0.f ? s : 0.f;
        }
        for (int pix = tid; pix < NVALID; pix += 256) {
            int h = 0, base = 0;
            while (pix >= base + (64 - h)) { base += 64 - h; h++; }
            int w = h + (pix - base);
            pix2hw[pix] = h * 64 + w;
        }
    } else if (blockIdx.x <= 16) {
        int i = ((blockIdx.x - 1) * 256 + tid) * 16;
        #pragma unroll
        for (int j = 0; j < 16; j++) w2b[i + j] = (bf16)w2[i + j];
    } else {
        int i = ((blockIdx.x - 17) * 256 + tid) * 4;
        float4 v = *(const float4*)(w3 + i);
        w3b[i+0] = (bf16)v.x; w3b[i+1] = (bf16)v.y;
        w3b[i+2] = (bf16)v.z; w3b[i+3] = (bf16)v.w;
    }
}

// ---------------- maskT[pix][s][t] bf16: gather valid cols + transpose -------
__global__ __launch_bounds__(256) void k_maskT(const float* __restrict__ mask,
                                               const int* __restrict__ pix2hw,
                                               bf16* __restrict__ maskT) {
    int tid = threadIdx.x;
    int pix = blockIdx.x * 64 + (tid & 63);
    if (pix >= NVALID) return;
    int combo = blockIdx.y * 4 + (tid >> 6);
    int s = combo >> 3, tc = combo & 7;
    int colo = s * 4096 + pix2hw[pix];
    bf16x8 v[4];
    #pragma unroll
    for (int i = 0; i < 32; i++) {
        float f = mask[(size_t)(tc * 32 + i) * 131072 + colo];
        v[i >> 3][i & 7] = (bf16)f;
    }
    bf16* dst = maskT + (size_t)pix * 8192 + s * 256 + tc * 32;
    #pragma unroll
    for (int k = 0; k < 4; k++) *(bf16x8*)(dst + k * 8) = v[k];
}

// ---------------- GEMM2: bm[n=(b,p)][k=(c,s)] = maskT @ xb_b^T ---------------
// 1-D grid 4160, groups of 64: xcd=id&7, b=(id>>3)&7, ps=(id>>6)*8+xcd.
__global__ __launch_bounds__(256, 4) void k_gemm2(const bf16* __restrict__ maskT,
                                                  const bf16* __restrict__ xb,
                                                  bf16* __restrict__ bm) {
    __shared__ __align__(16) char lds[33024];
    bf16* As0 = (bf16*)lds;              // [2][128][32]
    bf16* Bs0 = (bf16*)(lds + 16384);    // [2][128][32]
    bf16* T2  = (bf16*)lds;              // [4][4104] epilogue transpose

    int tid = threadIdx.x, lane = tid & 63, wave = tid >> 6;
    int m16 = lane & 15, q = lane >> 4;
    int wm = wave >> 1, wn = wave & 1;
    int id = blockIdx.x;
    int b = (id >> 3) & 7;
    int pst = (id >> 6) * 8 + (id & 7);
    int ps0 = pst * 128;
    const bf16* Ag = maskT + (size_t)ps0 * 256;
    const bf16* Bg = xb + (size_t)b * 32768;

    f32x4 acc[4][4];
    #pragma unroll
    for (int i = 0; i < 4; i++)
        #pragma unroll
        for (int j = 0; j < 4; j++) acc[i][j] = (f32x4){0.f, 0.f, 0.f, 0.f};

    stage16(Ag, 256, wave * 32,      0, As0, lane);
    stage16(Ag, 256, wave * 32 + 16, 0, As0, lane);
    stage16(Bg, 256, wave * 32,      0, Bs0, lane);
    stage16(Bg, 256, wave * 32 + 16, 0, Bs0, lane);

    for (int ks = 0; ks < 8; ks++) {
        __syncthreads();
        if (ks < 7) {
            int k0 = (ks + 1) * 32, o = ((ks + 1) & 1) * 4096;
            stage16(Ag, 256, wave * 32,      k0, As0 + o, lane);
            stage16(Ag, 256, wave * 32 + 16, k0, As0 + o, lane);
            stage16(Bg, 256, wave * 32,      k0, Bs0 + o, lane);
            stage16(Bg, 256, wave * 32 + 16, k0, Bs0 + o, lane);
        }
        const bf16* Ac = As0 + (ks & 1) * 4096;
        const bf16* Bc = Bs0 + (ks & 1) * 4096;
        bf16x8 af[4], bfv[4];
        #pragma unroll
        for (int i = 0; i < 4; i++) af[i]  = fragld(Ac, wm * 64 + i * 16 + m16, q);
        #pragma unroll
        for (int j = 0; j < 4; j++) bfv[j] = fragld(Bc, wn * 64 + j * 16 + m16, q);
        #pragma unroll
        for (int i = 0; i < 4; i++)
            #pragma unroll
            for (int j = 0; j < 4; j++)
                acc[i][j] = __builtin_amdgcn_mfma_f32_16x16x32_bf16(af[i], bfv[j], acc[i][j], 0, 0, 0);
    }
    __syncthreads();
    #pragma unroll
    for (int i = 0; i < 4; i++)
        #pragma unroll
        for (int r = 0; r < 4; r++) {
            int m = wm * 64 + i * 16 + q * 4 + r;
            int p_l = m >> 5, s = m & 31;
            #pragma unroll
            for (int j = 0; j < 4; j++) {
                int c = wn * 64 + j * 16 + m16;
                int K = (c >> 2) & 3;
                T2[p_l * 4104 + c * 32 + (s ^ (K << 3))] = (bf16)acc[i][j][r];
            }
        }
    __syncthreads();
    int n_l = tid >> 6, seg = tid & 63;
    bf16* dst = bm + ((size_t)b * NVALID + pst * 4 + n_l) * (size_t)KDIM;
    #pragma unroll
    for (int m2 = 0; m2 < 8; m2++) {
        int cblk = seg * 2 + (m2 >> 2), sblk = m2 & 3;
        int K = (cblk >> 2) & 3;
        *(bf16x8*)(dst + cblk * 32 + sblk * 8) =
            *(const bf16x8*)(T2 + n_l * 4104 + cblk * 32 + ((sblk ^ K) << 3));
    }
}

// ---------------- zero partial buffer ----------------------------------------
__global__ __launch_bounds__(256) void k_zero(float* __restrict__ p) {
    size_t i = ((size_t)blockIdx.x * 256 + threadIdx.x) * 16;
    #pragma unroll
    for (int j = 0; j < 4; j++) *(f32x4*)(p + i + j * 4) = (f32x4){0.f,0.f,0.f,0.f};
}

// ---------------- GEMM3 split-K: partial[n][o] += w3b_slice @ bm_slice^T -----
// Tile 128o x 128n, K-slice 2048 (64 iters), grid 1040 (4 blocks/CU).
// ids [0,1024): xcd=id&7; combo=(id>>3)&7: ot=combo&3, kt=combo>>2;
//               nt=(id>>6)*8+xcd.  ids [1024,1040): r: nt=128+(r&1),
//               ot=(r>>1)&3, kt=r>>3.  8 combos of one nt share an XCD.
__global__ __launch_bounds__(256, 4) void k_gemm3s(const bf16* __restrict__ w3b,
                                                   const bf16* __restrict__ bm,
                                                   float* __restrict__ part) {
    __shared__ __align__(16) char lds[34816];
    bf16*  As0 = (bf16*)lds;             // [2][128][32]
    bf16*  Bs0 = (bf16*)(lds + 16384);   // [2][128][32]
    float* T2f = (float*)lds;            // [64][132] epilogue (33792 B)

    int tid = threadIdx.x, lane = tid & 63, wave = tid >> 6;
    int m16 = lane & 15, q = lane >> 4;
    int wm = wave >> 1, wn = wave & 1;
    int id = blockIdx.x, nt, ot, kt;
    if (id >= 1024) { int r = id - 1024; nt = 128 + (r & 1); ot = (r >> 1) & 3; kt = r >> 3; }
    else            { int combo = (id >> 3) & 7; nt = (id >> 6) * 8 + (id & 7); ot = combo & 3; kt = combo >> 2; }
    int n0 = nt * 128, o0 = ot * 128;
    const bf16* Ag = w3b + (size_t)o0 * KDIM + kt * 2048;
    const bf16* Bg = bm + (size_t)n0 * KDIM + kt * 2048;

    f32x4 acc[4][4];
    #pragma unroll
    for (int i = 0; i < 4; i++)
        #pragma unroll
        for (int j = 0; j < 4; j++) acc[i][j] = (f32x4){0.f, 0.f, 0.f, 0.f};

    stage16(Ag, KDIM, wave * 32,      0, As0, lane);
    stage16(Ag, KDIM, wave * 32 + 16, 0, As0, lane);
    stage16(Bg, KDIM, wave * 32,      0, Bs0, lane);
    stage16(Bg, KDIM, wave * 32 + 16, 0, Bs0, lane);

    for (int ks = 0; ks < 64; ks++) {
        __syncthreads();
        if (ks < 63) {
            int k0 = (ks + 1) * 32, o = ((ks + 1) & 1) * 4096;
            stage16(Ag, KDIM, wave * 32,      k0, As0 + o, lane);
            stage16(Ag, KDIM, wave * 32 + 16, k0, As0 + o, lane);
            stage16(Bg, KDIM, wave * 32,      k0, Bs0 + o, lane);
            stage16(Bg, KDIM, wave * 32 + 16, k0, Bs0 + o, lane);
        }
        const bf16* Ac = As0 + (ks & 1) * 4096;
        const bf16* Bc = Bs0 + (ks & 1) * 4096;
        bf16x8 af[4], bfv[4];
        #pragma unroll
        for (int i = 0; i < 4; i++) af[i]  = fragld(Ac, wm * 64 + i * 16 + m16, q);
        #pragma unroll
        for (int j = 0; j < 4; j++) bfv[j] = fragld(Bc, wn * 64 + j * 16 + m16, q);
        #pragma unroll
        for (int i = 0; i < 4; i++)
            #pragma unroll
            for (int j = 0; j < 4; j++)
                acc[i][j] = __builtin_amdgcn_mfma_f32_16x16x32_bf16(af[i], bfv[j], acc[i][j], 0, 0, 0);
    }
    // Epilogue: per 64-n chunk, transpose to LDS then coalesced atomicAdd.
    #pragma unroll
    for (int chunk = 0; chunk < 2; chunk++) {
        __syncthreads();
        if (wn == chunk) {
            #pragma unroll
            for (int i = 0; i < 4; i++)
                #pragma unroll
                for (int r = 0; r < 4; r++) {
                    int o_l = wm * 64 + i * 16 + q * 4 + r;
                    #pragma unroll
                    for (int j = 0; j < 4; j++) {
                        int n_l = j * 16 + m16;
                        T2f[n_l * 132 + o_l] = acc[i][j][r];
                    }
                }
        }
        __syncthreads();
        #pragma unroll
        for (int m = 0; m < 32; m++) {
            int idx = m * 256 + tid;
            int n_l = idx >> 7, o_l = idx & 127;
            atomicAdd(part + (size_t)(n0 + chunk * 64 + n_l) * 512 + o0 + o_l,
                      T2f[n_l * 132 + o_l]);
        }
    }
}

// ---------------- combine: x3[n][o] = relu(part + b3) cast bf16 --------------
__global__ __launch_bounds__(256) void k_combine(const float* __restrict__ part,
                                                 const float* __restrict__ b3,
                                                 bf16* __restrict__ x3) {
    size_t i = ((size_t)blockIdx.x * 256 + threadIdx.x) * 8;
    int o = (int)(i & 511);
    f32x4 a = *(const f32x4*)(part + i);
    f32x4 b = *(const f32x4*)(part + i + 4);
    f32x4 ba = *(const f32x4*)(b3 + o);
    f32x4 bb = *(const f32x4*)(b3 + o + 4);
    bf16x8 r;
    #pragma unroll
    for (int j = 0; j < 4; j++) {
        float v = a[j] + ba[j]; v = v > 0.f ? v : 0.f; r[j] = (bf16)v;
        float w = b[j] + bb[j]; w = w > 0.f ? w : 0.f; r[j+4] = (bf16)w;
    }
    *(bf16x8*)(x3 + i) = r;
}

// ---------------- GEMM3 fallback (R3-exact): grid 520 ------------------------
__global__ __launch_bounds__(256, 2) void k_gemm3f(const bf16* __restrict__ w3b,
                                                   const bf16* __restrict__ bm,
                                                   const float* __restrict__ b3,
                                                   bf16* __restrict__ x3) {
    __shared__ __align__(16) char lds[34816];
    bf16* As0 = (bf16*)lds;
    bf16* Bs0 = (bf16*)(lds + 16384);
    bf16* T2  = (bf16*)lds;

    int tid = threadIdx.x, lane = tid & 63, wave = tid >> 6;
    int m16 = lane & 15, q = lane >> 4;
    int wm = wave >> 1, wn = wave & 1;
    int id = blockIdx.x, nt, ot;
    if (id >= 512) { int r = id - 512; nt = 128 + (r & 1); ot = r >> 1; }
    else           { nt = (id >> 5) * 8 + (id & 7); ot = (id >> 3) & 3; }
    int n0 = nt * 128, o0 = ot * 128;
    const bf16* Ag = w3b + (size_t)o0 * KDIM;
    const bf16* Bg = bm + (size_t)n0 * KDIM;

    f32x4 acc[4][4];
    #pragma unroll
    for (int i = 0; i < 4; i++)
        #pragma unroll
        for (int j = 0; j < 4; j++) acc[i][j] = (f32x4){0.f, 0.f, 0.f, 0.f};

    stage16(Ag, KDIM, wave * 32,      0, As0, lane);
    stage16(Ag, KDIM, wave * 32 + 16, 0, As0, lane);
    stage16(Bg, KDIM, wave * 32,      0, Bs0, lane);
    stage16(Bg, KDIM, wave * 32 + 16, 0, Bs0, lane);

    for (int ks = 0; ks < 128; ks++) {
        __syncthreads();
        if (ks < 127) {
            int k0 = (ks + 1) * 32, o = ((ks + 1) & 1) * 4096;
            stage16(Ag, KDIM, wave * 32,      k0, As0 + o, lane);
            stage16(Ag, KDIM, wave * 32 + 16, k0, As0 + o, lane);
            stage16(Bg, KDIM, wave * 32,      k0, Bs0 + o, lane);
            stage16(Bg, KDIM, wave * 32 + 16, k0, Bs0 + o, lane);
        }
        const bf16* Ac = As0 + (ks & 1) * 4096;
        const bf16* Bc = Bs0 + (ks & 1) * 4096;
        bf16x8 af[4], bfv[4];
        #pragma unroll
        for (int i = 0; i < 4; i++) af[i]  = fragld(Ac, wm * 64 + i * 16 + m16, q);
        #pragma unroll
        for (int j = 0; j < 4; j++) bfv[j] = fragld(Bc, wn * 64 + j * 16 + m16, q);
        #pragma unroll
        for (int i = 0; i < 4; i++)
            #pragma unroll
            for (int j = 0; j < 4; j++)
                acc[i][j] = __builtin_amdgcn_mfma_f32_16x16x32_bf16(af[i], bfv[j], acc[i][j], 0, 0, 0);
    }
    __syncthreads();
    #pragma unroll
    for (int i = 0; i < 4; i++)
        #pragma unroll
        for (int r = 0; r < 4; r++) {
            int o_l = wm * 64 + i * 16 + q * 4 + r;
            float bias = b3[o0 + o_l];
            #pragma unroll
            for (int j = 0; j < 4; j++) {
                int n_l = wn * 64 + j * 16 + m16;
                float v = acc[i][j][r] + bias; v = v > 0.f ? v : 0.f;
                T2[n_l * 136 + o_l] = (bf16)v;
            }
        }
    __syncthreads();
    {
        int n_l = tid >> 1, half = (tid & 1) * 64;
        bf16* dst = x3 + (size_t)(n0 + n_l) * 512 + o0 + half;
        const bf16* src = T2 + n_l * 136 + half;
        #pragma unroll
        for (int m = 0; m < 8; m++)
            *(bf16x8*)(dst + m * 8) = *(const bf16x8*)(src + m * 8);
    }
}

// ---------------- GEMM4: out = relu(w2b @ x3^T + b2), K=512 ------------------
__global__ __launch_bounds__(256, 2) void k_gemm4(const bf16* __restrict__ w2b,
                                                  const bf16* __restrict__ x3,
                                                  const float* __restrict__ b2,
                                                  const int* __restrict__ pix2hw,
                                                  float* __restrict__ out) {
    __shared__ __align__(16) char lds[24576];
    bf16* As0 = (bf16*)lds;
    bf16* Bs0 = (bf16*)(lds + 16384);

    int tid = threadIdx.x, lane = tid & 63, wave = tid >> 6;
    int m16 = lane & 15, q = lane >> 4;
    int n0 = blockIdx.x * 64;
    const bf16* Ag = w2b;
    const bf16* Bg = x3 + (size_t)n0 * 512;

    f32x4 acc[2][4];
    #pragma unroll
    for (int i = 0; i < 2; i++)
        #pragma unroll
        for (int j = 0; j < 4; j++) acc[i][j] = (f32x4){0.f, 0.f, 0.f, 0.f};

    stage16(Ag, 512, wave * 32,      0, As0, lane);
    stage16(Ag, 512, wave * 32 + 16, 0, As0, lane);
    stage16(Bg, 512, wave * 16,      0, Bs0, lane);

    for (int ks = 0; ks < 16; ks++) {
        __syncthreads();
        if (ks < 15) {
            int k0 = (ks + 1) * 32, oA = ((ks + 1) & 1) * 4096, oB = ((ks + 1) & 1) * 2048;
            stage16(Ag, 512, wave * 32,      k0, As0 + oA, lane);
            stage16(Ag, 512, wave * 32 + 16, k0, As0 + oA, lane);
            stage16(Bg, 512, wave * 16,      k0, Bs0 + oB, lane);
        }
        const bf16* Ac = As0 + (ks & 1) * 4096;
        const bf16* Bc = Bs0 + (ks & 1) * 2048;
        bf16x8 af[2], bfv[4];
        #pragma unroll
        for (int i = 0; i < 2; i++) af[i]  = fragld(Ac, wave * 32 + i * 16 + m16, q);
        #pragma unroll
        for (int j = 0; j < 4; j++) bfv[j] = fragld(Bc, j * 16 + m16, q);
        #pragma unroll
        for (int i = 0; i < 2; i++)
            #pragma unroll
            for (int j = 0; j < 4; j++)
                acc[i][j] = __builtin_amdgcn_mfma_f32_16x16x32_bf16(af[i], bfv[j], acc[i][j], 0, 0, 0);
    }
    int barr[4], hwarr[4];
    #pragma unroll
    for (int j = 0; j < 4; j++) {
        int n = n0 + j * 16 + m16;
        int bb = n / NVALID;
        barr[j] = bb; hwarr[j] = pix2hw[n - bb * NVALID];
    }
    #pragma unroll
    for (int i = 0; i < 2; i++)
        #pragma unroll
        for (int r = 0; r < 4; r++) {
            int o2 = wave * 32 + i * 16 + q * 4 + r;
            float bias = b2[o2];
            #pragma unroll
            for (int j = 0; j < 4; j++) {
                float v = acc[i][j][r] + bias; v = v > 0.f ? v : 0.f;
                out[(size_t)barr[j] * 524288 + o2 * 4096 + hwarr[j]] = v;
            }
        }
}

// ---------------- fill invalid (w < h) pixels with constant vector -----------
__global__ __launch_bounds__(256) void k_fill(const float* __restrict__ cvec,
                                              float* __restrict__ out) {
    int bo = blockIdx.x;
    float v = cvec[bo & 127];
    float* dst = out + (size_t)bo * 4096;
    for (int hw = threadIdx.x; hw < 4096; hw += 256) {
        int h = hw >> 6, w = hw & 63;
        if (w < h) dst[hw] = v;
    }
}

extern "C" void kernel_launch(void* const* d_in, const int* in_sizes, int n_in,
                              void* d_out, int out_size, void* d_ws, size_t ws_size,
                              hipStream_t stream) {
    const float* base = (const float*)d_in[0];
    const float* w1   = (const float*)d_in[1];
    const float* b1   = (const float*)d_in[2];
    const float* w3   = (const float*)d_in[3];
    const float* b3   = (const float*)d_in[4];
    const float* w2   = (const float*)d_in[5];
    const float* b2   = (const float*)d_in[6];
    const float* mask = (const float*)d_in[7];
    float* out = (float*)d_out;
    char* ws = (char*)d_ws;
    bf16*  xb     = (bf16*)(ws + OFF_XB);
    bf16*  w3b    = (bf16*)(ws + OFF_W3B);
    bf16*  w2b    = (bf16*)(ws + OFF_W2B);
    float* cvec   = (float*)(ws + OFF_CVEC);
    int*   pix2hw = (int*)(ws + OFF_PIX);
    bf16*  maskT  = (bf16*)(ws + OFF_MASKT);
    bf16*  bm     = (bf16*)(ws + OFF_BM);
    float* part   = (float*)(ws + OFF_MASKT);   // reuses maskT region (34 MB, exact)
    bool split = (ws_size >= (size_t)WS_SPLIT);
    bf16* x3 = split ? (bf16*)(ws + OFF_X3T) : (bf16*)(ws + OFF_MASKT);

    k_conv<<<dim3(32, 8), dim3(256), 0, stream>>>(base, w1, b1, xb);
    k_misc<<<dim3(2065), dim3(256), 0, stream>>>(w2, b2, b3, w3, w2b, w3b, cvec, pix2hw);
    k_maskT<<<dim3(33, 64), dim3(256), 0, stream>>>(mask, pix2hw, maskT);
    k_gemm2<<<dim3(4160), dim3(256), 0, stream>>>(maskT, xb, bm);
    if (split) {
        k_zero<<<dim3(2080), dim3(256), 0, stream>>>(part);
        k_gemm3s<<<dim3(1040), dim3(256), 0, stream>>>(w3b, bm, part);
        k_combine<<<dim3(4160), dim3(256), 0, stream>>>(part, b3, x3);
    } else {
        k_gemm3f<<<dim3(520), dim3(256), 0, stream>>>(w3b, bm, b3, x3);
    }
    k_gemm4<<<dim3(260), dim3(256), 0, stream>>>(w2b, x3, b2, pix2hw, out);
    k_fill<<<dim3(1024), dim3(256), 0, stream>>>(cvec, out);
}

// Round 6
// 396.433 us; speedup vs baseline: 1.2861x; 1.2861x over previous
//
#include <hip/hip_runtime.h>
#include <stdint.h>
#include <math.h>

typedef __bf16 bf16;
typedef __bf16 bf16x8 __attribute__((ext_vector_type(8)));
typedef float  f32x4  __attribute__((ext_vector_type(4)));

#define NVALID 2080            // D*(D+1)/2 valid (h<=w) pixels
#define NCOLS  16640           // B*NVALID  (bm rows, n-dim)
#define KDIM   4096            // NS*C2D    (bm cols, k = s*128+c)

// ws layout (bytes)
#define OFF_XBT   0u           // bf16 [8][256][128] xbT = 512 KB
#define OFF_W3B   524288u      // bf16 [512][4096] (k = s*128+c) = 4 MB
#define OFF_W2B   4718592u     // bf16 [128][512]
#define OFF_CVEC  4849664u     // f32  [128]
#define OFF_PIX   4850176u     // int  [2080]
#define OFF_X3    8388608u     // bf16 [16640][512] = 17 MB
#define OFF_TABW  25427968u    // f32  [2080][32][8] = 2.13 MB
#define OFF_TABT  27557888u    // int  [2080][32][8] = 2.13 MB
#define OFF_BM    42991616u    // bf16 [16640][4096] = 136 MB (ends 179,306,496)

__device__ __forceinline__ void gload_lds16(const void* g, void* l) {
    __builtin_amdgcn_global_load_lds(
        (const __attribute__((address_space(1))) void*)g,
        (__attribute__((address_space(3))) void*)l, 16, 0, 0);
}

// Stage 16 rows x 32 k (bf16) into LDS with XOR swizzle.
__device__ __forceinline__ void stage16(const bf16* gbase, int stride, int rbase,
                                        int k0, bf16* ldsbase, int lane) {
    int row = rbase + (lane >> 2);
    int cg  = (lane & 3) ^ ((row >> 1) & 3);
    gload_lds16(gbase + (size_t)row * stride + k0 + cg * 8, ldsbase + rbase * 32);
}

__device__ __forceinline__ bf16x8 fragld(const bf16* lds, int row, int q) {
    int c = q ^ ((row >> 1) & 3);
    return *(const bf16x8*)(lds + row * 32 + c * 8);
}

// ---------------- conv1d(k=3,pad=1) + relu + cast -> xbT[b][t][c] ------------
__global__ __launch_bounds__(256) void k_conv(const float* __restrict__ base,
                                              const float* __restrict__ w1,
                                              const float* __restrict__ b1,
                                              bf16* __restrict__ xbT) {
    __shared__ float sb[256][10];
    int ttile = blockIdx.x, b = blockIdx.y;
    int t0 = ttile * 8, tid = threadIdx.x;
    for (int ci = tid; ci < 256; ci += 256) {
        const float* src = base + (size_t)(b * 256 + ci) * 256;
        #pragma unroll
        for (int j = 0; j < 10; j++) {
            int t = t0 - 1 + j;
            sb[ci][j] = (t >= 0 && t < 256) ? src[t] : 0.f;
        }
    }
    __syncthreads();
    int co = tid & 127, th = tid >> 7;
    float bias = b1[co];
    float acc[4] = {bias, bias, bias, bias};
    const float* wp = w1 + (size_t)co * 768;
    int tl = th * 4;
    for (int ci = 0; ci < 256; ci++) {
        float wa = wp[ci*3+0], wb = wp[ci*3+1], wc = wp[ci*3+2];
        #pragma unroll
        for (int j = 0; j < 4; j++)
            acc[j] += sb[ci][tl+j]*wa + sb[ci][tl+j+1]*wb + sb[ci][tl+j+2]*wc;
    }
    bf16* dst = xbT + ((size_t)b * 256 + t0 + tl) * 128 + co;
    #pragma unroll
    for (int j = 0; j < 4; j++) {
        float v = acc[j] > 0.f ? acc[j] : 0.f;
        dst[j * 128] = (bf16)v;
    }
}

// ---------------- misc: cvec, pix2hw, w2 cast, w3 transpose-cast -------------
// grid 529: block 0 = cvec+pix2hw, 1..16 = w2 cast, 17..528 = w3 (one o each)
__global__ __launch_bounds__(256) void k_misc(const float* __restrict__ w2,
                                              const float* __restrict__ b2,
                                              const float* __restrict__ b3,
                                              const float* __restrict__ w3,
                                              bf16* __restrict__ w2b,
                                              bf16* __restrict__ w3b,
                                              float* __restrict__ cvec,
                                              int* __restrict__ pix2hw) {
    int tid = threadIdx.x;
    if (blockIdx.x == 0) {
        if (tid < 128) {
            float s = b2[tid];
            for (int o = 0; o < 512; o++) {
                float r = b3[o]; r = r > 0.f ? r : 0.f;
                s += w2[(size_t)tid * 512 + o] * r;
            }
            cvec[tid] = s > 0.f ? s : 0.f;
        }
        for (int pix = tid; pix < NVALID; pix += 256) {
            int h = 0, base = 0;
            while (pix >= base + (64 - h)) { base += 64 - h; h++; }
            int w = h + (pix - base);
            pix2hw[pix] = h * 64 + w;
        }
    } else if (blockIdx.x <= 16) {
        int i = ((blockIdx.x - 1) * 256 + tid) * 16;
        #pragma unroll
        for (int j = 0; j < 16; j++) w2b[i + j] = (bf16)w2[i + j];
    } else {
        // transpose one o row: w3[o][c][s] -> w3b[o][s*128+c]
        __shared__ float l[128 * 33];
        int o = blockIdx.x - 17;
        const float* src = w3 + (size_t)o * 4096;
        #pragma unroll
        for (int m = 0; m < 16; m++) {
            int i = m * 256 + tid;
            int c = i >> 5, s = i & 31;
            l[c * 33 + s] = src[i];
        }
        __syncthreads();
        bf16* d = w3b + (size_t)o * 4096;
        #pragma unroll
        for (int m = 0; m < 16; m++) {
            int k = m * 256 + tid;
            int s = k >> 7, c = k & 127;
            d[k] = (bf16)l[c * 33 + s];
        }
    }
}

// ---------------- table: per (pix,s) 6 (t, weight) pairs, double-exact -------
__global__ __launch_bounds__(256) void k_table(float* __restrict__ tabw,
                                               int* __restrict__ tabt) {
    int idx = blockIdx.x * 256 + threadIdx.x;   // p*32+s
    if (idx >= NVALID * 32) return;
    int p = idx >> 5, s = idx & 31;
    int h = 0, base = 0;
    while (p >= base + (64 - h)) { base += 64 - h; h++; }
    int w = h + (p - base);
    double sp = 4.0 * h, ep = 4.0 * (w + 1);
    double L = ep - sp + 1.0;
    double start_p = sp - L * 0.5;
    double end_p   = ep + L * 0.5;
    double step = (end_p - start_p) / 95.0;
    float* wd = tabw + (size_t)idx * 8;
    int*   td = tabt + (size_t)idx * 8;
    #pragma unroll
    for (int i = 0; i < 3; i++) {
        double pos = start_p + step * (3 * s + i);
        double tr = trunc(pos);
        double fr = pos - tr;
        int it = (int)tr;
        bool ok = (it >= 0 && it < 255);
        wd[i*2+0] = ok ? (float)((1.0 - fr) / 3.0) : 0.f;
        td[i*2+0] = ok ? it : 0;
        wd[i*2+1] = ok ? (float)(fr / 3.0) : 0.f;
        td[i*2+1] = ok ? it + 1 : 0;
    }
    wd[6] = 0.f; wd[7] = 0.f; td[6] = 0; td[7] = 0;
}

// ---------------- bm sparse: bm[n=(b,p)][s*128+c] = sum_j w_j xbT[b][t_j][c] -
// grid 4160 x 256 thr; one wave per bm row.
__global__ __launch_bounds__(256) void k_bm(const bf16* __restrict__ xbT,
                                            const float* __restrict__ tabw,
                                            const int* __restrict__ tabt,
                                            bf16* __restrict__ bm) {
    int lane = threadIdx.x & 63;
    int n = __builtin_amdgcn_readfirstlane(blockIdx.x * 4 + (threadIdx.x >> 6));
    int b = n / NVALID, p = n - b * NVALID;
    const bf16* xs = xbT + (size_t)b * 32768;
    bf16* dst = bm + (size_t)n * (size_t)KDIM;
    for (int s = 0; s < 32; s++) {
        const float* wv = tabw + (size_t)(p * 32 + s) * 8;
        const int*   tv = tabt + (size_t)(p * 32 + s) * 8;
        float a0 = 0.f, a1 = 0.f;
        #pragma unroll
        for (int j = 0; j < 6; j++) {
            float w = wv[j];
            int   t = tv[j];
            uint32_t x = *(const uint32_t*)(xs + t * 128 + lane * 2);
            union { uint32_t u; float f; } lo, hi;
            lo.u = x << 16;
            hi.u = x & 0xffff0000u;
            a0 += w * lo.f;
            a1 += w * hi.f;
        }
        union { uint32_t u; bf16 h[2]; } o;
        o.h[0] = (bf16)a0; o.h[1] = (bf16)a1;
        *(uint32_t*)(dst + s * 128 + lane * 2) = o.u;
    }
}

// ---------------- GEMM3 (R3-proven): x3[n][o] = relu(w3b @ bm^T + b3) --------
// 1-D grid 520. ids [0,512): xcd=id&7, o=(id>>3)&3, n=(id>>5)*8+xcd;
// ids [512,520): r=id-512, n=128+(r&1), o=r>>1.
__global__ __launch_bounds__(256, 2) void k_gemm3f(const bf16* __restrict__ w3b,
                                                   const bf16* __restrict__ bm,
                                                   const float* __restrict__ b3,
                                                   bf16* __restrict__ x3) {
    __shared__ __align__(16) char lds[34816];
    bf16* As0 = (bf16*)lds;
    bf16* Bs0 = (bf16*)(lds + 16384);
    bf16* T2  = (bf16*)lds;

    int tid = threadIdx.x, lane = tid & 63, wave = tid >> 6;
    int m16 = lane & 15, q = lane >> 4;
    int wm = wave >> 1, wn = wave & 1;
    int id = blockIdx.x, nt, ot;
    if (id >= 512) { int r = id - 512; nt = 128 + (r & 1); ot = r >> 1; }
    else           { nt = (id >> 5) * 8 + (id & 7); ot = (id >> 3) & 3; }
    int n0 = nt * 128, o0 = ot * 128;
    const bf16* Ag = w3b + (size_t)o0 * KDIM;
    const bf16* Bg = bm + (size_t)n0 * KDIM;

    f32x4 acc[4][4];
    #pragma unroll
    for (int i = 0; i < 4; i++)
        #pragma unroll
        for (int j = 0; j < 4; j++) acc[i][j] = (f32x4){0.f, 0.f, 0.f, 0.f};

    stage16(Ag, KDIM, wave * 32,      0, As0, lane);
    stage16(Ag, KDIM, wave * 32 + 16, 0, As0, lane);
    stage16(Bg, KDIM, wave * 32,      0, Bs0, lane);
    stage16(Bg, KDIM, wave * 32 + 16, 0, Bs0, lane);

    for (int ks = 0; ks < 128; ks++) {
        __syncthreads();
        if (ks < 127) {
            int k0 = (ks + 1) * 32, o = ((ks + 1) & 1) * 4096;
            stage16(Ag, KDIM, wave * 32,      k0, As0 + o, lane);
            stage16(Ag, KDIM, wave * 32 + 16, k0, As0 + o, lane);
            stage16(Bg, KDIM, wave * 32,      k0, Bs0 + o, lane);
            stage16(Bg, KDIM, wave * 32 + 16, k0, Bs0 + o, lane);
        }
        const bf16* Ac = As0 + (ks & 1) * 4096;
        const bf16* Bc = Bs0 + (ks & 1) * 4096;
        bf16x8 af[4], bfv[4];
        #pragma unroll
        for (int i = 0; i < 4; i++) af[i]  = fragld(Ac, wm * 64 + i * 16 + m16, q);
        #pragma unroll
        for (int j = 0; j < 4; j++) bfv[j] = fragld(Bc, wn * 64 + j * 16 + m16, q);
        #pragma unroll
        for (int i = 0; i < 4; i++)
            #pragma unroll
            for (int j = 0; j < 4; j++)
                acc[i][j] = __builtin_amdgcn_mfma_f32_16x16x32_bf16(af[i], bfv[j], acc[i][j], 0, 0, 0);
    }
    __syncthreads();
    #pragma unroll
    for (int i = 0; i < 4; i++)
        #pragma unroll
        for (int r = 0; r < 4; r++) {
            int o_l = wm * 64 + i * 16 + q * 4 + r;
            float bias = b3[o0 + o_l];
            #pragma unroll
            for (int j = 0; j < 4; j++) {
                int n_l = wn * 64 + j * 16 + m16;
                float v = acc[i][j][r] + bias; v = v > 0.f ? v : 0.f;
                T2[n_l * 136 + o_l] = (bf16)v;
            }
        }
    __syncthreads();
    {
        int n_l = tid >> 1, half = (tid & 1) * 64;
        bf16* dst = x3 + (size_t)(n0 + n_l) * 512 + o0 + half;
        const bf16* src = T2 + n_l * 136 + half;
        #pragma unroll
        for (int m = 0; m < 8; m++)
            *(bf16x8*)(dst + m * 8) = *(const bf16x8*)(src + m * 8);
    }
}

// ---------------- GEMM4: out = relu(w2b @ x3^T + b2), K=512 ------------------
__global__ __launch_bounds__(256, 2) void k_gemm4(const bf16* __restrict__ w2b,
                                                  const bf16* __restrict__ x3,
                                                  const float* __restrict__ b2,
                                                  const int* __restrict__ pix2hw,
                                                  float* __restrict__ out) {
    __shared__ __align__(16) char lds[24576];
    bf16* As0 = (bf16*)lds;
    bf16* Bs0 = (bf16*)(lds + 16384);

    int tid = threadIdx.x, lane = tid & 63, wave = tid >> 6;
    int m16 = lane & 15, q = lane >> 4;
    int n0 = blockIdx.x * 64;
    const bf16* Ag = w2b;
    const bf16* Bg = x3 + (size_t)n0 * 512;

    f32x4 acc[2][4];
    #pragma unroll
    for (int i = 0; i < 2; i++)
        #pragma unroll
        for (int j = 0; j < 4; j++) acc[i][j] = (f32x4){0.f, 0.f, 0.f, 0.f};

    stage16(Ag, 512, wave * 32,      0, As0, lane);
    stage16(Ag, 512, wave * 32 + 16, 0, As0, lane);
    stage16(Bg, 512, wave * 16,      0, Bs0, lane);

    for (int ks = 0; ks < 16; ks++) {
        __syncthreads();
        if (ks < 15) {
            int k0 = (ks + 1) * 32, oA = ((ks + 1) & 1) * 4096, oB = ((ks + 1) & 1) * 2048;
            stage16(Ag, 512, wave * 32,      k0, As0 + oA, lane);
            stage16(Ag, 512, wave * 32 + 16, k0, As0 + oA, lane);
            stage16(Bg, 512, wave * 16,      k0, Bs0 + oB, lane);
        }
        const bf16* Ac = As0 + (ks & 1) * 4096;
        const bf16* Bc = Bs0 + (ks & 1) * 2048;
        bf16x8 af[2], bfv[4];
        #pragma unroll
        for (int i = 0; i < 2; i++) af[i]  = fragld(Ac, wave * 32 + i * 16 + m16, q);
        #pragma unroll
        for (int j = 0; j < 4; j++) bfv[j] = fragld(Bc, j * 16 + m16, q);
        #pragma unroll
        for (int i = 0; i < 2; i++)
            #pragma unroll
            for (int j = 0; j < 4; j++)
                acc[i][j] = __builtin_amdgcn_mfma_f32_16x16x32_bf16(af[i], bfv[j], acc[i][j], 0, 0, 0);
    }
    int barr[4], hwarr[4];
    #pragma unroll
    for (int j = 0; j < 4; j++) {
        int n = n0 + j * 16 + m16;
        int bb = n / NVALID;
        barr[j] = bb; hwarr[j] = pix2hw[n - bb * NVALID];
    }
    #pragma unroll
    for (int i = 0; i < 2; i++)
        #pragma unroll
        for (int r = 0; r < 4; r++) {
            int o2 = wave * 32 + i * 16 + q * 4 + r;
            float bias = b2[o2];
            #pragma unroll
            for (int j = 0; j < 4; j++) {
                float v = acc[i][j][r] + bias; v = v > 0.f ? v : 0.f;
                out[(size_t)barr[j] * 524288 + o2 * 4096 + hwarr[j]] = v;
            }
        }
}

// ---------------- fill invalid (w < h) pixels with constant vector -----------
__global__ __launch_bounds__(256) void k_fill(const float* __restrict__ cvec,
                                              float* __restrict__ out) {
    int bo = blockIdx.x;
    float v = cvec[bo & 127];
    float* dst = out + (size_t)bo * 4096;
    for (int hw = threadIdx.x; hw < 4096; hw += 256) {
        int h = hw >> 6, w = hw & 63;
        if (w < h) dst[hw] = v;
    }
}

extern "C" void kernel_launch(void* const* d_in, const int* in_sizes, int n_in,
                              void* d_out, int out_size, void* d_ws, size_t ws_size,
                              hipStream_t stream) {
    const float* base = (const float*)d_in[0];
    const float* w1   = (const float*)d_in[1];
    const float* b1   = (const float*)d_in[2];
    const float* w3   = (const float*)d_in[3];
    const float* b3   = (const float*)d_in[4];
    const float* w2   = (const float*)d_in[5];
    const float* b2   = (const float*)d_in[6];
    float* out = (float*)d_out;
    char* ws = (char*)d_ws;
    bf16*  xbT    = (bf16*)(ws + OFF_XBT);
    bf16*  w3b    = (bf16*)(ws + OFF_W3B);
    bf16*  w2b    = (bf16*)(ws + OFF_W2B);
    float* cvec   = (float*)(ws + OFF_CVEC);
    int*   pix2hw = (int*)(ws + OFF_PIX);
    bf16*  x3     = (bf16*)(ws + OFF_X3);
    float* tabw   = (float*)(ws + OFF_TABW);
    int*   tabt   = (int*)(ws + OFF_TABT);
    bf16*  bm     = (bf16*)(ws + OFF_BM);

    k_conv<<<dim3(32, 8), dim3(256), 0, stream>>>(base, w1, b1, xbT);
    k_misc<<<dim3(529), dim3(256), 0, stream>>>(w2, b2, b3, w3, w2b, w3b, cvec, pix2hw);
    k_table<<<dim3(260), dim3(256), 0, stream>>>(tabw, tabt);
    k_bm<<<dim3(4160), dim3(256), 0, stream>>>(xbT, tabw, tabt, bm);
    k_gemm3f<<<dim3(520), dim3(256), 0, stream>>>(w3b, bm, b3, x3);
    k_gemm4<<<dim3(260), dim3(256), 0, stream>>>(w2b, x3, b2, pix2hw, out);
    k_fill<<<dim3(1024), dim3(256), 0, stream>>>(cvec, out);
}

// Round 7
// 384.726 us; speedup vs baseline: 1.3252x; 1.0304x over previous
//
#include <hip/hip_runtime.h>
#include <stdint.h>
#include <math.h>

typedef __bf16 bf16;
typedef __bf16 bf16x8 __attribute__((ext_vector_type(8)));
typedef float  f32x4  __attribute__((ext_vector_type(4)));

#define NVALID 2080            // D*(D+1)/2 valid (h<=w) pixels
#define NCOLS  16640           // B*NVALID  (bm rows, n-dim)
#define KDIM   4096            // NS*C2D    (bm cols, k = s*128+c)

// ws layout (bytes)
#define OFF_XBT   0u           // bf16 [8][256][128] xbT = 512 KB
#define OFF_W3B   524288u      // bf16 [512][4096] (k = s*128+c) = 4 MB
#define OFF_W2B   4718592u     // bf16 [128][512]
#define OFF_CVEC  4849664u     // f32  [128]
#define OFF_PIX   4850176u     // int  [2080]
#define OFF_W1T   4980736u     // f32  [768][128] = 393,216 B
#define OFF_X3    8388608u     // bf16 [16640][512] = 17 MB
#define OFF_TABW  25427968u    // f32  [2080][32][8] = 2.13 MB
#define OFF_TABT  27557888u    // int  [2080][32][8] = 2.13 MB
#define OFF_BM    42991616u    // bf16 [16640][4096] = 136 MB (ends 179,306,496)

__device__ __forceinline__ void gload_lds16(const void* g, void* l) {
    __builtin_amdgcn_global_load_lds(
        (const __attribute__((address_space(1))) void*)g,
        (__attribute__((address_space(3))) void*)l, 16, 0, 0);
}

// Stage 16 rows x 32 k (bf16) into LDS with XOR swizzle.
__device__ __forceinline__ void stage16(const bf16* gbase, int stride, int rbase,
                                        int k0, bf16* ldsbase, int lane) {
    int row = rbase + (lane >> 2);
    int cg  = (lane & 3) ^ ((row >> 1) & 3);
    gload_lds16(gbase + (size_t)row * stride + k0 + cg * 8, ldsbase + rbase * 32);
}

__device__ __forceinline__ bf16x8 fragld(const bf16* lds, int row, int q) {
    int c = q ^ ((row >> 1) & 3);
    return *(const bf16x8*)(lds + row * 32 + c * 8);
}

// ---------------- misc mega-kernel ------------------------------------------
// grid 813: 0 = cvec+pix2hw; 1..16 = w2 cast; 17..528 = w3 transpose;
//           529..552 = w1 transpose; 553..812 = sample table
__global__ __launch_bounds__(256) void k_misc(const float* __restrict__ w1,
                                              const float* __restrict__ w2,
                                              const float* __restrict__ b2,
                                              const float* __restrict__ b3,
                                              const float* __restrict__ w3,
                                              float* __restrict__ w1T,
                                              bf16* __restrict__ w2b,
                                              bf16* __restrict__ w3b,
                                              float* __restrict__ cvec,
                                              int* __restrict__ pix2hw,
                                              float* __restrict__ tabw,
                                              int* __restrict__ tabt) {
    int tid = threadIdx.x, bx = blockIdx.x;
    if (bx == 0) {
        int wv = tid >> 6, ln = tid & 63;
        for (int c = wv; c < 128; c += 4) {
            const float* row = w2 + (size_t)c * 512 + ln * 8;
            float p = 0.f;
            #pragma unroll
            for (int k = 0; k < 8; k++) {
                float r = b3[ln * 8 + k]; r = r > 0.f ? r : 0.f;
                p += row[k] * r;
            }
            #pragma unroll
            for (int off = 32; off; off >>= 1) p += __shfl_down(p, off);
            if (ln == 0) {
                p += b2[c];
                cvec[c] = p > 0.f ? p : 0.f;
            }
        }
        for (int pix = tid; pix < NVALID; pix += 256) {
            int h = 0, base = 0;
            while (pix >= base + (64 - h)) { base += 64 - h; h++; }
            int w = h + (pix - base);
            pix2hw[pix] = h * 64 + w;
        }
    } else if (bx <= 16) {
        int i = ((bx - 1) * 256 + tid) * 16;
        #pragma unroll
        for (int j = 0; j < 16; j++) w2b[i + j] = (bf16)w2[i + j];
    } else if (bx <= 528) {
        // transpose one o row: w3[o][c][s] -> w3b[o][s*128+c]
        __shared__ float l[128 * 33];
        int o = bx - 17;
        const float* src = w3 + (size_t)o * 4096;
        #pragma unroll
        for (int m = 0; m < 16; m++) {
            int i = m * 256 + tid;
            int c = i >> 5, s = i & 31;
            l[c * 33 + s] = src[i];
        }
        __syncthreads();
        bf16* d = w3b + (size_t)o * 4096;
        #pragma unroll
        for (int m = 0; m < 16; m++) {
            int k = m * 256 + tid;
            int s = k >> 7, c = k & 127;
            d[k] = (bf16)l[c * 33 + s];
        }
    } else if (bx <= 552) {
        // w1[co][r] -> w1T[r][co], write-coalesced
        int idx0 = (bx - 529) * 4096 + tid * 16;
        int r = idx0 >> 7, co0 = idx0 & 127;
        float tmp[16];
        #pragma unroll
        for (int m = 0; m < 16; m++) tmp[m] = w1[(size_t)(co0 + m) * 768 + r];
        #pragma unroll
        for (int m = 0; m < 4; m++)
            *(f32x4*)(w1T + idx0 + m * 4) = *(const f32x4*)(tmp + m * 4);
    } else {
        // sample table: per (pix,s) 6 (t, weight) pairs, double-exact
        int idx = (bx - 553) * 256 + tid;   // p*32+s
        if (idx >= NVALID * 32) return;
        int p = idx >> 5, s = idx & 31;
        int h = 0, base = 0;
        while (p >= base + (64 - h)) { base += 64 - h; h++; }
        int w = h + (p - base);
        double sp = 4.0 * h, ep = 4.0 * (w + 1);
        double L = ep - sp + 1.0;
        double start_p = sp - L * 0.5;
        double end_p   = ep + L * 0.5;
        double step = (end_p - start_p) / 95.0;
        float* wd = tabw + (size_t)idx * 8;
        int*   td = tabt + (size_t)idx * 8;
        #pragma unroll
        for (int i = 0; i < 3; i++) {
            double pos = start_p + step * (3 * s + i);
            double tr = trunc(pos);
            double fr = pos - tr;
            int it = (int)tr;
            bool ok = (it >= 0 && it < 255);
            wd[i*2+0] = ok ? (float)((1.0 - fr) / 3.0) : 0.f;
            td[i*2+0] = ok ? it : 0;
            wd[i*2+1] = ok ? (float)(fr / 3.0) : 0.f;
            td[i*2+1] = ok ? it + 1 : 0;
        }
        wd[6] = 0.f; wd[7] = 0.f; td[6] = 0; td[7] = 0;
    }
}

// ---------------- conv1d(k=3,pad=1) + relu + cast -> xbT[b][t][c] ------------
// w1T[r][co] layout: all weight loads coalesced (256 B/wave).
__global__ __launch_bounds__(256) void k_conv(const float* __restrict__ base,
                                              const float* __restrict__ w1T,
                                              const float* __restrict__ b1,
                                              bf16* __restrict__ xbT) {
    __shared__ float sb[256][10];
    int ttile = blockIdx.x, b = blockIdx.y;
    int t0 = ttile * 8, tid = threadIdx.x;
    for (int ci = tid; ci < 256; ci += 256) {
        const float* src = base + (size_t)(b * 256 + ci) * 256;
        #pragma unroll
        for (int j = 0; j < 10; j++) {
            int t = t0 - 1 + j;
            sb[ci][j] = (t >= 0 && t < 256) ? src[t] : 0.f;
        }
    }
    __syncthreads();
    int co = tid & 127, th = tid >> 7;
    float bias = b1[co];
    float acc[4] = {bias, bias, bias, bias};
    const float* wt = w1T + co;
    int tl = th * 4;
    for (int ci = 0; ci < 256; ci++) {
        float wa = wt[(ci*3+0) * 128];
        float wb = wt[(ci*3+1) * 128];
        float wc = wt[(ci*3+2) * 128];
        #pragma unroll
        for (int j = 0; j < 4; j++)
            acc[j] += sb[ci][tl+j]*wa + sb[ci][tl+j+1]*wb + sb[ci][tl+j+2]*wc;
    }
    bf16* dst = xbT + ((size_t)b * 256 + t0 + tl) * 128 + co;
    #pragma unroll
    for (int j = 0; j < 4; j++) {
        float v = acc[j] > 0.f ? acc[j] : 0.f;
        dst[j * 128] = (bf16)v;
    }
}

// ---------------- bm sparse: bm[n=(b,p)][s*128+c] = sum_j w_j xbT[b][t_j][c] -
// grid 4160 x 256 thr; one wave per bm row.
__global__ __launch_bounds__(256) void k_bm(const bf16* __restrict__ xbT,
                                            const float* __restrict__ tabw,
                                            const int* __restrict__ tabt,
                                            bf16* __restrict__ bm) {
    int lane = threadIdx.x & 63;
    int n = __builtin_amdgcn_readfirstlane(blockIdx.x * 4 + (threadIdx.x >> 6));
    int b = n / NVALID, p = n - b * NVALID;
    const bf16* xs = xbT + (size_t)b * 32768;
    bf16* dst = bm + (size_t)n * (size_t)KDIM;
    for (int s = 0; s < 32; s++) {
        const float* wv = tabw + (size_t)(p * 32 + s) * 8;
        const int*   tv = tabt + (size_t)(p * 32 + s) * 8;
        float a0 = 0.f, a1 = 0.f;
        #pragma unroll
        for (int j = 0; j < 6; j++) {
            float w = wv[j];
            int   t = tv[j];
            uint32_t x = *(const uint32_t*)(xs + t * 128 + lane * 2);
            union { uint32_t u; float f; } lo, hi;
            lo.u = x << 16;
            hi.u = x & 0xffff0000u;
            a0 += w * lo.f;
            a1 += w * hi.f;
        }
        union { uint32_t u; bf16 h[2]; } o;
        o.h[0] = (bf16)a0; o.h[1] = (bf16)a1;
        *(uint32_t*)(dst + s * 128 + lane * 2) = o.u;
    }
}

// ---------------- GEMM3 (R3-proven): x3[n][o] = relu(w3b @ bm^T + b3) --------
// 1-D grid 520. ids [0,512): xcd=id&7, o=(id>>3)&3, n=(id>>5)*8+xcd;
// ids [512,520): r=id-512, n=128+(r&1), o=r>>1.
__global__ __launch_bounds__(256, 2) void k_gemm3f(const bf16* __restrict__ w3b,
                                                   const bf16* __restrict__ bm,
                                                   const float* __restrict__ b3,
                                                   bf16* __restrict__ x3) {
    __shared__ __align__(16) char lds[34816];
    bf16* As0 = (bf16*)lds;
    bf16* Bs0 = (bf16*)(lds + 16384);
    bf16* T2  = (bf16*)lds;

    int tid = threadIdx.x, lane = tid & 63, wave = tid >> 6;
    int m16 = lane & 15, q = lane >> 4;
    int wm = wave >> 1, wn = wave & 1;
    int id = blockIdx.x, nt, ot;
    if (id >= 512) { int r = id - 512; nt = 128 + (r & 1); ot = r >> 1; }
    else           { nt = (id >> 5) * 8 + (id & 7); ot = (id >> 3) & 3; }
    int n0 = nt * 128, o0 = ot * 128;
    const bf16* Ag = w3b + (size_t)o0 * KDIM;
    const bf16* Bg = bm + (size_t)n0 * KDIM;

    f32x4 acc[4][4];
    #pragma unroll
    for (int i = 0; i < 4; i++)
        #pragma unroll
        for (int j = 0; j < 4; j++) acc[i][j] = (f32x4){0.f, 0.f, 0.f, 0.f};

    stage16(Ag, KDIM, wave * 32,      0, As0, lane);
    stage16(Ag, KDIM, wave * 32 + 16, 0, As0, lane);
    stage16(Bg, KDIM, wave * 32,      0, Bs0, lane);
    stage16(Bg, KDIM, wave * 32 + 16, 0, Bs0, lane);

    for (int ks = 0; ks < 128; ks++) {
        __syncthreads();
        if (ks < 127) {
            int k0 = (ks + 1) * 32, o = ((ks + 1) & 1) * 4096;
            stage16(Ag, KDIM, wave * 32,      k0, As0 + o, lane);
            stage16(Ag, KDIM, wave * 32 + 16, k0, As0 + o, lane);
            stage16(Bg, KDIM, wave * 32,      k0, Bs0 + o, lane);
            stage16(Bg, KDIM, wave * 32 + 16, k0, Bs0 + o, lane);
        }
        const bf16* Ac = As0 + (ks & 1) * 4096;
        const bf16* Bc = Bs0 + (ks & 1) * 4096;
        bf16x8 af[4], bfv[4];
        #pragma unroll
        for (int i = 0; i < 4; i++) af[i]  = fragld(Ac, wm * 64 + i * 16 + m16, q);
        #pragma unroll
        for (int j = 0; j < 4; j++) bfv[j] = fragld(Bc, wn * 64 + j * 16 + m16, q);
        #pragma unroll
        for (int i = 0; i < 4; i++)
            #pragma unroll
            for (int j = 0; j < 4; j++)
                acc[i][j] = __builtin_amdgcn_mfma_f32_16x16x32_bf16(af[i], bfv[j], acc[i][j], 0, 0, 0);
    }
    __syncthreads();
    #pragma unroll
    for (int i = 0; i < 4; i++)
        #pragma unroll
        for (int r = 0; r < 4; r++) {
            int o_l = wm * 64 + i * 16 + q * 4 + r;
            float bias = b3[o0 + o_l];
            #pragma unroll
            for (int j = 0; j < 4; j++) {
                int n_l = wn * 64 + j * 16 + m16;
                float v = acc[i][j][r] + bias; v = v > 0.f ? v : 0.f;
                T2[n_l * 136 + o_l] = (bf16)v;
            }
        }
    __syncthreads();
    {
        int n_l = tid >> 1, half = (tid & 1) * 64;
        bf16* dst = x3 + (size_t)(n0 + n_l) * 512 + o0 + half;
        const bf16* src = T2 + n_l * 136 + half;
        #pragma unroll
        for (int m = 0; m < 8; m++)
            *(bf16x8*)(dst + m * 8) = *(const bf16x8*)(src + m * 8);
    }
}

// ---------------- GEMM4 + fill: blocks [0,260) gemm, [260,1284) fill ---------
__global__ __launch_bounds__(256, 2) void k_gemm4(const bf16* __restrict__ w2b,
                                                  const bf16* __restrict__ x3,
                                                  const float* __restrict__ b2,
                                                  const int* __restrict__ pix2hw,
                                                  const float* __restrict__ cvec,
                                                  float* __restrict__ out) {
    __shared__ __align__(16) char lds[24576];
    if (blockIdx.x >= 260) {
        int bo = blockIdx.x - 260;           // b*128 + o2
        float v = cvec[bo & 127];
        float* dst = out + (size_t)bo * 4096;
        for (int hw = threadIdx.x; hw < 4096; hw += 256) {
            int h = hw >> 6, w = hw & 63;
            if (w < h) dst[hw] = v;
        }
        return;
    }
    bf16* As0 = (bf16*)lds;
    bf16* Bs0 = (bf16*)(lds + 16384);

    int tid = threadIdx.x, lane = tid & 63, wave = tid >> 6;
    int m16 = lane & 15, q = lane >> 4;
    int n0 = blockIdx.x * 64;
    const bf16* Ag = w2b;
    const bf16* Bg = x3 + (size_t)n0 * 512;

    f32x4 acc[2][4];
    #pragma unroll
    for (int i = 0; i < 2; i++)
        #pragma unroll
        for (int j = 0; j < 4; j++) acc[i][j] = (f32x4){0.f, 0.f, 0.f, 0.f};

    stage16(Ag, 512, wave * 32,      0, As0, lane);
    stage16(Ag, 512, wave * 32 + 16, 0, As0, lane);
    stage16(Bg, 512, wave * 16,      0, Bs0, lane);

    for (int ks = 0; ks < 16; ks++) {
        __syncthreads();
        if (ks < 15) {
            int k0 = (ks + 1) * 32, oA = ((ks + 1) & 1) * 4096, oB = ((ks + 1) & 1) * 2048;
            stage16(Ag, 512, wave * 32,      k0, As0 + oA, lane);
            stage16(Ag, 512, wave * 32 + 16, k0, As0 + oA, lane);
            stage16(Bg, 512, wave * 16,      k0, Bs0 + oB, lane);
        }
        const bf16* Ac = As0 + (ks & 1) * 4096;
        const bf16* Bc = Bs0 + (ks & 1) * 2048;
        bf16x8 af[2], bfv[4];
        #pragma unroll
        for (int i = 0; i < 2; i++) af[i]  = fragld(Ac, wave * 32 + i * 16 + m16, q);
        #pragma unroll
        for (int j = 0; j < 4; j++) bfv[j] = fragld(Bc, j * 16 + m16, q);
        #pragma unroll
        for (int i = 0; i < 2; i++)
            #pragma unroll
            for (int j = 0; j < 4; j++)
                acc[i][j] = __builtin_amdgcn_mfma_f32_16x16x32_bf16(af[i], bfv[j], acc[i][j], 0, 0, 0);
    }
    int barr[4], hwarr[4];
    #pragma unroll
    for (int j = 0; j < 4; j++) {
        int n = n0 + j * 16 + m16;
        int bb = n / NVALID;
        barr[j] = bb; hwarr[j] = pix2hw[n - bb * NVALID];
    }
    #pragma unroll
    for (int i = 0; i < 2; i++)
        #pragma unroll
        for (int r = 0; r < 4; r++) {
            int o2 = wave * 32 + i * 16 + q * 4 + r;
            float bias = b2[o2];
            #pragma unroll
            for (int j = 0; j < 4; j++) {
                float v = acc[i][j][r] + bias; v = v > 0.f ? v : 0.f;
                out[(size_t)barr[j] * 524288 + o2 * 4096 + hwarr[j]] = v;
            }
        }
}

extern "C" void kernel_launch(void* const* d_in, const int* in_sizes, int n_in,
                              void* d_out, int out_size, void* d_ws, size_t ws_size,
                              hipStream_t stream) {
    const float* base = (const float*)d_in[0];
    const float* w1   = (const float*)d_in[1];
    const float* b1   = (const float*)d_in[2];
    const float* w3   = (const float*)d_in[3];
    const float* b3   = (const float*)d_in[4];
    const float* w2   = (const float*)d_in[5];
    const float* b2   = (const float*)d_in[6];
    float* out = (float*)d_out;
    char* ws = (char*)d_ws;
    bf16*  xbT    = (bf16*)(ws + OFF_XBT);
    bf16*  w3b    = (bf16*)(ws + OFF_W3B);
    bf16*  w2b    = (bf16*)(ws + OFF_W2B);
    float* cvec   = (float*)(ws + OFF_CVEC);
    int*   pix2hw = (int*)(ws + OFF_PIX);
    float* w1T    = (float*)(ws + OFF_W1T);
    bf16*  x3     = (bf16*)(ws + OFF_X3);
    float* tabw   = (float*)(ws + OFF_TABW);
    int*   tabt   = (int*)(ws + OFF_TABT);
    bf16*  bm     = (bf16*)(ws + OFF_BM);

    k_misc<<<dim3(813), dim3(256), 0, stream>>>(w1, w2, b2, b3, w3, w1T, w2b, w3b,
                                                cvec, pix2hw, tabw, tabt);
    k_conv<<<dim3(32, 8), dim3(256), 0, stream>>>(base, w1T, b1, xbT);
    k_bm<<<dim3(4160), dim3(256), 0, stream>>>(xbT, tabw, tabt, bm);
    k_gemm3f<<<dim3(520), dim3(256), 0, stream>>>(w3b, bm, b3, x3);
    k_gemm4<<<dim3(1284), dim3(256), 0, stream>>>(w2b, x3, b2, pix2hw, cvec, out);
}